// Round 5
// baseline (947.361 us; speedup 1.0000x reference)
//
#include <hip/hip_runtime.h>
#include <cstdint>
#include <cstddef>

#define NNODES 50000
#define NREL   16
#define DIM    200
#define NEDGE  400000
#define NBLK   782                      // ceil(NNODES/64)
#define NKEY   (NBLK * 1024)            // 800768, key = (dst>>6)*1024 + r*64 + (dst&63)
#define NPART  (NKEY / 256)             // 3128
#define WTREL  46592                    // elements per relation tile: 91 frags x 512
#define WTSZ   (17 * WTREL)             // 17 relation tiles (16 + root)
#define MAXB   12                       // batched gathers per round (wave-chunk deg: Poisson λ=8)
#define PCAP   1280                     // per-block perm staging cap (expected 512, Poisson)
#define GTOT   119                      // 17 relations x 7 ks-groups, linear stream
#define BFRAG  13312                    // 13 fragments x 1024 B staged per group

typedef __attribute__((ext_vector_type(8))) short short8;   // 8 bf16
typedef __attribute__((ext_vector_type(4))) float floatx4;  // MFMA C/D

__device__ __forceinline__ unsigned short f2bf(float f) {
    unsigned int u = __float_as_uint(f);
    u = (u + 0x7FFFu + ((u >> 16) & 1u)) >> 16;   // RNE
    return (unsigned short)u;
}
__device__ __forceinline__ float bf2f(unsigned short h) {
    return __uint_as_float(((unsigned int)h) << 16);
}

// ---------- preprocessing: counting sort by block-major key ----------

__device__ __forceinline__ int edge_key(int d, int r) {
    return (d >> 6) * 1024 + r * 64 + (d & 63);
}

__global__ void count_kernel(const int* __restrict__ ei, const int* __restrict__ et,
                             int* __restrict__ cnt) {
    int e = blockIdx.x * 256 + threadIdx.x;
    if (e < NEDGE) atomicAdd(&cnt[edge_key(ei[NEDGE + e], et[e])], 1);
}

__global__ void scan1_kernel(const int* __restrict__ cnt, int* __restrict__ rp,
                             int* __restrict__ part) {
    __shared__ int sc[256];
    int b = blockIdx.x, t = threadIdx.x, i = b * 256 + t;
    int v = cnt[i];
    sc[t] = v; __syncthreads();
    for (int off = 1; off < 256; off <<= 1) {
        int x = (t >= off) ? sc[t - off] : 0;
        __syncthreads();
        sc[t] += x;
        __syncthreads();
    }
    int incl = sc[t];
    rp[i] = incl - v;
    if (t == 255) part[b] = incl;
}

__global__ void scan2_kernel(int* __restrict__ p) {
    __shared__ int sc[256];
    __shared__ int carry_s;
    int t = threadIdx.x;
    if (t == 0) carry_s = 0;
    __syncthreads();
    for (int base = 0; base < NPART; base += 256) {
        int i = base + t;
        int v = (i < NPART) ? p[i] : 0;
        sc[t] = v; __syncthreads();
        for (int off = 1; off < 256; off <<= 1) {
            int x = (t >= off) ? sc[t - off] : 0;
            __syncthreads();
            sc[t] += x;
            __syncthreads();
        }
        int incl = sc[t];
        int carry = carry_s;
        if (i < NPART) p[i] = carry + incl - v;
        __syncthreads();
        if (t == 255) carry_s = carry + incl;
        __syncthreads();
    }
    if (t == 0) p[NPART] = carry_s;   // == NEDGE
}

__global__ void scan3_kernel(int* __restrict__ rp, int* __restrict__ cursor,
                             const int* __restrict__ part) {
    int i = blockIdx.x * 256 + threadIdx.x;
    if (i < NKEY) {
        int v = rp[i] + part[i >> 8];
        rp[i] = v;
        cursor[i] = v;
    } else if (i == NKEY) {
        rp[i] = part[NPART];
    }
}

// perm[pos] = (row_in_block << 16) | src   (src < 50000 fits 16 bits)
__global__ void scatter_kernel(const int* __restrict__ ei, const int* __restrict__ et,
                               int* __restrict__ cursor, int* __restrict__ perm) {
    int e = blockIdx.x * 256 + threadIdx.x;
    if (e < NEDGE) {
        int d = ei[NEDGE + e];
        int pos = atomicAdd(&cursor[edge_key(d, et[e])], 1);
        perm[pos] = ((d & 63) << 16) | ei[e];
    }
}

// ---------- W^T prep: fragment-ordered layout ----------
// WT[r] is 91 fragments (ks 0..6, nt 0..12), each a contiguous 1024 B block
// consumed by one wave as lane*16. Group g = r*7+ks has its 13 nt-fragments
// at byte offset (13*g + nt)*1024 -> the whole WT is a linear 119 x 13 KB
// stream for the fused kernel's staging pipeline. r==16 is root.
__global__ void wt_kernel(const float* __restrict__ W, const float* __restrict__ root,
                          unsigned short* __restrict__ WT) {
    int idx = blockIdx.x * 256 + threadIdx.x;
    if (idx >= WTSZ) return;
    int r = idx / WTREL;
    int rem = idx - r * WTREL;
    int blk = rem >> 9;            // 0..90 = ks*13 + nt
    int within = rem & 511;
    int ks = blk / 13;
    int nt = blk - ks * 13;
    int lane = within >> 3;
    int j = within & 7;
    int mn = lane & 15, quad = lane >> 4;
    int n = nt * 16 + mn;
    int k = ks * 32 + quad * 8 + j;
    float v = 0.f;
    if (n < DIM && k < DIM)
        v = (r < 16) ? W[((size_t)r * DIM + k) * DIM + n] : root[(size_t)k * DIM + n];
    WT[idx] = f2bf(v);
}

// ---------- fused layer ----------
// Lockstep barrier-clocked pipeline over 119 (relation, ks) B-groups.
// B-fragments are staged cooperatively into an LDS double buffer:
//   iter g: [gather(rel) if ks==0] ld_issue(g+2 -> regs) ; ds_write(g+1 from
//           regs loaded last iter) ; process(g) ; __syncthreads().
// ld_issue(g+2) is issued a full phase before its consuming ds_write, so the
// __syncthreads() vmcnt(0) drain finds it already (or nearly) complete — the
// safe barrier costs ~nothing while removing the hand-rolled raw-s_barrier
// template (round-4 container failure suspect).
// As stays wave-private (each wave MFMAs its 16 rows vs the shared B buffer).
// LDS = 25.7 (As) + 26 (B dbuf) + 5 (pLds) = 57.4 KB -> 2 blocks/CU.
template<bool SRC_F32, bool OUT_RELU_BF16>
__global__ __launch_bounds__(256, 2) void fused_kernel(
        const void* __restrict__ srcv, const unsigned short* __restrict__ WT,
        const int* __restrict__ rp, const int* __restrict__ perm,
        const float* __restrict__ bias, void* __restrict__ outv) {
    __shared__ __align__(16) char As[25664];   // 64 rows x 400 B bf16 + 64 B slack
    __shared__ __align__(16) char Bs[2 * BFRAG];
    __shared__ int pLds[PCAP];                 // staged perm segment for this block
    const int t = threadIdx.x;
    const int w = t >> 6;
    const int lane = t & 63;
    const int quad = lane >> 4;
    const int mn = lane & 15;
    const int v0 = blockIdx.x * 64;
    const int kbase = blockIdx.x * 1024;
    const bool colok = (lane < 50);
    const int nf = (w == 0) ? 4 : 3;           // fragments staged by this wave

    // descriptor loads overlap the LDS zeroing
    const int li = (lane < 16) ? lane : 15;
    const int b0 = rp[kbase + li * 64 + (w << 4)];
    const int b1 = rp[kbase + li * 64 + (w << 4) + 16];
    const int pbase = rp[kbase];             // block's perm segment [pbase, pend)
    const int pend  = rp[kbase + 1024];
    const int pcnt  = pend - pbase;
    const bool staged = (pcnt <= PCAP);      // block-uniform

    for (int i = t; i < 25664 / 16; i += 256)
        *(float4*)(As + i * 16) = make_float4(0.f, 0.f, 0.f, 0.f);
    if (staged)
        for (int i = t; i < pcnt; i += 256) pLds[i] = perm[pbase + i];
    __syncthreads();

    const float* srcf = (const float*)srcv;
    const unsigned short* srcb = (const unsigned short*)srcv;

    floatx4 acc[13];
    #pragma unroll
    for (int i = 0; i < 13; ++i) acc[i] = (floatx4){0.f, 0.f, 0.f, 0.f};

    // ---- staging pipeline pieces ----
    auto ld_issue = [&](int g, uint4* R) {       // global -> regs, this wave's frags
        const char* gb = (const char*)WT + (size_t)(13 * g) * 1024 + (lane << 4);
        #pragma unroll
        for (int i = 0; i < 4; ++i)
            if (i < nf) R[i] = *(const uint4*)(gb + ((i << 2) + w) * 1024);
    };
    auto st_grp = [&](int g, const uint4* R) {   // regs -> LDS buffer (g&1)
        char* bb = Bs + (g & 1) * BFRAG + (lane << 4);
        #pragma unroll
        for (int i = 0; i < 4; ++i)
            if (i < nf) *(uint4*)(bb + ((i << 2) + w) * 1024) = R[i];
    };
    auto process = [&](int g) {                  // 1 af ds_read + 13 bf ds_read + 13 MFMA
        const int ks = g % 7;
        const short8 af = *(const short8*)(As + ((w << 4) + mn) * 400 + (quad << 4) + ks * 64);
        const char* bb = Bs + (g & 1) * BFRAG + (lane << 4);
        short8 bf[13];
        #pragma unroll
        for (int nt = 0; nt < 13; ++nt)
            bf[nt] = *(const short8*)(bb + nt * 1024);
        #pragma unroll
        for (int nt = 0; nt < 13; ++nt)
            acc[nt] = __builtin_amdgcn_mfma_f32_16x16x32_bf16(af, bf[nt], acc[nt], 0, 0, 0);
    };
    auto zero_rows = [&]() {   // zero this wave's 16 rows (6400 B)
        char* base = As + w * 6400;
        #pragma unroll
        for (int i = 0; i < 6; ++i)
            *(float4*)(base + i * 1024 + lane * 16) = make_float4(0.f, 0.f, 0.f, 0.f);
        if (lane < 16)
            *(float4*)(base + 6144 + lane * 16) = make_float4(0.f, 0.f, 0.f, 0.f);
    };

    auto gather = [&](int rel) {   // fill As (wave-private rows) for relation rel
        zero_rows();
        if (rel < NREL) {
            const int ws = __builtin_amdgcn_readlane(b0, rel);
            const int we = __builtin_amdgcn_readlane(b1, rel);
            if (ws >= we) return;
            int curM = -1, curCnt = 0;
            float s0 = 0.f, s1 = 0.f, s2 = 0.f, s3 = 0.f;
            auto flush = [&]() {
                if (curM >= 0 && colok) {
                    float sc = 1.0f / (float)curCnt;
                    ushort4 pk;
                    pk.x = f2bf(s0 * sc); pk.y = f2bf(s1 * sc);
                    pk.z = f2bf(s2 * sc); pk.w = f2bf(s3 * sc);
                    *(ushort4*)(As + curM * 400 + lane * 8) = pk;
                }
            };
            for (int jb = ws; jb < we; jb += MAXB) {
                const int nb = min(we - jb, MAXB);
                const int sel = (lane < nb) ? lane : (nb - 1);
                int pmv;
                if (staged) pmv = pLds[jb - pbase + sel];
                else        pmv = perm[jb + sel];
                int pms[MAXB];
                #pragma unroll
                for (int i = 0; i < MAXB; ++i)
                    pms[i] = __builtin_amdgcn_readlane(pmv, i);
                float4  qf[MAXB];
                ushort4 qb[MAXB];
                #pragma unroll
                for (int i = 0; i < MAXB; ++i) {
                    if (i < nb && colok) {
                        const int sv = pms[i] & 0xFFFF;
                        if (SRC_F32) qf[i] = *(const float4*)(srcf + (size_t)sv * DIM + (lane << 2));
                        else         qb[i] = *(const ushort4*)(srcb + (size_t)sv * DIM + (lane << 2));
                    }
                }
                #pragma unroll
                for (int i = 0; i < MAXB; ++i) {
                    if (i < nb) {
                        const int m = pms[i] >> 16;
                        float f0, f1, f2, f3;
                        if (SRC_F32) { f0 = qf[i].x; f1 = qf[i].y; f2 = qf[i].z; f3 = qf[i].w; }
                        else { f0 = bf2f(qb[i].x); f1 = bf2f(qb[i].y); f2 = bf2f(qb[i].z); f3 = bf2f(qb[i].w); }
                        if (m != curM) {
                            flush();
                            curM = m; curCnt = 1;
                            s0 = f0; s1 = f1; s2 = f2; s3 = f3;
                        } else {
                            ++curCnt;
                            s0 += f0; s1 += f1; s2 += f2; s3 += f3;
                        }
                    }
                }
            }
            flush();
        } else {
            // root: A = x rows directly (two batches of 8 independent loads)
            #pragma unroll
            for (int g2 = 0; g2 < 2; ++g2) {
                float4  qf[8];
                ushort4 qb[8];
                #pragma unroll
                for (int i = 0; i < 8; ++i) {
                    const int v = v0 + (w << 4) + g2 * 8 + i;
                    if (v < NNODES && colok) {
                        if (SRC_F32) qf[i] = *(const float4*)(srcf + (size_t)v * DIM + (lane << 2));
                        else         qb[i] = *(const ushort4*)(srcb + (size_t)v * DIM + (lane << 2));
                    }
                }
                #pragma unroll
                for (int i = 0; i < 8; ++i) {
                    const int m = (w << 4) + g2 * 8 + i;
                    if (v0 + m < NNODES && colok) {
                        ushort4 pk;
                        if (SRC_F32) {
                            pk.x = f2bf(qf[i].x); pk.y = f2bf(qf[i].y);
                            pk.z = f2bf(qf[i].z); pk.w = f2bf(qf[i].w);
                        } else pk = qb[i];
                        *(ushort4*)(As + m * 400 + lane * 8) = pk;
                    }
                }
            }
        }
    };

    // ---- prologue: fill the pipe (group 0 staged, group 1 loads in flight) ----
    uint4 RA[4], RB[4];
    ld_issue(0, RA);
    st_grp(0, RA);                 // compiler waits only RA's loads
    ld_issue(1, RB);
    __syncthreads();

    // ---- main loop: one barrier per group, prefetch issued a phase early ----
    auto iter = [&](int g, uint4* Rfill, uint4* Rwr) {
        if (g % 7 == 0) gather(g / 7);             // As is wave-private: no barrier
        if (g + 2 < GTOT) ld_issue(g + 2, Rfill);  // prefetch for next iteration
        if (g + 1 < GTOT) st_grp(g + 1, Rwr);      // waits only Rwr's loads
        process(g);
        __syncthreads();
    };
    #pragma unroll 1
    for (int gg = 0; gg < GTOT - 1; gg += 2) {
        iter(gg, RA, RB);
        iter(gg + 1, RB, RA);
    }
    iter(GTOT - 1, RA, RB);        // g = 118 (even parity)

    // epilogue: C row = quad*4 + i, col = nt*16 + mn
    float* outf = (float*)outv;
    unsigned short* outb = (unsigned short*)outv;
    #pragma unroll
    for (int nt = 0; nt < 13; ++nt) {
        const int col = nt * 16 + mn;
        if (col < DIM) {
            const float bv = bias[col];
            #pragma unroll
            for (int i = 0; i < 4; ++i) {
                const int v = v0 + (w << 4) + (quad << 2) + i;
                if (v < NNODES) {
                    float x = acc[nt][i] + bv;
                    if (OUT_RELU_BF16) {
                        x = fmaxf(x, 0.f);
                        outb[(size_t)v * DIM + col] = f2bf(x);
                    } else {
                        outf[(size_t)v * DIM + col] = x;
                    }
                }
            }
        }
    }
}

// ---------- launch ----------

extern "C" void kernel_launch(void* const* d_in, const int* in_sizes, int n_in,
                              void* d_out, int out_size, void* d_ws, size_t ws_size,
                              hipStream_t stream) {
    const int*   edge_index = (const int*)d_in[0];
    const int*   edge_type  = (const int*)d_in[1];
    const float* emb   = (const float*)d_in[2];
    const float* W1    = (const float*)d_in[3];
    const float* root1 = (const float*)d_in[4];
    const float* b1    = (const float*)d_in[5];
    const float* W2    = (const float*)d_in[6];
    const float* root2 = (const float*)d_in[7];
    const float* b2    = (const float*)d_in[8];
    float* out = (float*)d_out;

    // ws layout (bytes):
    //  cnt/cursor  0           3,203,072   (cnt dead after scan1; reused as cursor)
    //  rp          3,203,072   3,203,080
    //  part        6,406,152      12,520
    //  perm        6,418,672   1,600,000
    //  hbf         8,018,672  20,000,000
    //  WT1        28,018,672   1,584,128
    //  WT2        29,602,800   1,584,128   -> total ~31.2 MB
    char* ws = (char*)d_ws;
    int*            cnt    = (int*)(ws);
    int*            cursor = (int*)(ws);
    int*            rp     = (int*)(ws + 3203072);
    int*            part   = (int*)(ws + 6406152);
    int*            perm   = (int*)(ws + 6418672);
    unsigned short* hbf    = (unsigned short*)(ws + 8018672);
    unsigned short* WT1    = (unsigned short*)(ws + 28018672);
    unsigned short* WT2    = (unsigned short*)(ws + 29602800);

    hipMemsetAsync(cnt, 0, (size_t)NKEY * sizeof(int), stream);
    count_kernel<<<(NEDGE + 255) / 256, 256, 0, stream>>>(edge_index, edge_type, cnt);
    scan1_kernel<<<NPART, 256, 0, stream>>>(cnt, rp, part);
    scan2_kernel<<<1, 256, 0, stream>>>(part);
    scan3_kernel<<<(NKEY + 256) / 256 + 1, 256, 0, stream>>>(rp, cursor, part);
    scatter_kernel<<<(NEDGE + 255) / 256, 256, 0, stream>>>(edge_index, edge_type, cursor, perm);

    wt_kernel<<<(WTSZ + 255) / 256, 256, 0, stream>>>(W1, root1, WT1);
    wt_kernel<<<(WTSZ + 255) / 256, 256, 0, stream>>>(W2, root2, WT2);

    fused_kernel<true, true><<<NBLK, 256, 0, stream>>>(emb, WT1, rp, perm, b1, hbf);
    fused_kernel<false, false><<<NBLK, 256, 0, stream>>>(hbf, WT2, rp, perm, b2, out);
}

// Round 6
// 633.843 us; speedup vs baseline: 1.4946x; 1.4946x over previous
//
#include <hip/hip_runtime.h>
#include <cstdint>
#include <cstddef>

#define NNODES 50000
#define NREL   16
#define DIM    200
#define NEDGE  400000
#define NBLK   782                      // ceil(NNODES/64)
#define NKEY   (NBLK * 1024)            // 800768, key = (dst>>6)*1024 + r*64 + (dst&63)
#define NPART  (NKEY / 256)             // 3128
#define WTREL  46592                    // elements per relation tile: 91 frags x 512
#define WTSZ   (17 * WTREL)             // 17 relation tiles (16 + root)
#define MAXB   12                       // batched gathers per round (wave-chunk deg: Poisson λ=8)
#define PCAP   1280                     // per-block perm staging cap (expected 512, Poisson)
#define GTOT   119                      // 17 relations x 7 ks-groups, linear stream
#define BFRAG  13312                    // 13 fragments x 1024 B staged per group

typedef __attribute__((ext_vector_type(8))) short short8;   // 8 bf16
typedef __attribute__((ext_vector_type(4))) float floatx4;  // MFMA C/D

typedef __attribute__((address_space(1))) const unsigned int gas_u32;
typedef __attribute__((address_space(3))) unsigned int las_u32;

__device__ __forceinline__ unsigned short f2bf(float f) {
    unsigned int u = __float_as_uint(f);
    u = (u + 0x7FFFu + ((u >> 16) & 1u)) >> 16;   // RNE
    return (unsigned short)u;
}
__device__ __forceinline__ float bf2f(unsigned short h) {
    return __uint_as_float(((unsigned int)h) << 16);
}

// ---------- preprocessing: counting sort by block-major key ----------

__device__ __forceinline__ int edge_key(int d, int r) {
    return (d >> 6) * 1024 + r * 64 + (d & 63);
}

__global__ void count_kernel(const int* __restrict__ ei, const int* __restrict__ et,
                             int* __restrict__ cnt) {
    int e = blockIdx.x * 256 + threadIdx.x;
    if (e < NEDGE) atomicAdd(&cnt[edge_key(ei[NEDGE + e], et[e])], 1);
}

__global__ void scan1_kernel(const int* __restrict__ cnt, int* __restrict__ rp,
                             int* __restrict__ part) {
    __shared__ int sc[256];
    int b = blockIdx.x, t = threadIdx.x, i = b * 256 + t;
    int v = cnt[i];
    sc[t] = v; __syncthreads();
    for (int off = 1; off < 256; off <<= 1) {
        int x = (t >= off) ? sc[t - off] : 0;
        __syncthreads();
        sc[t] += x;
        __syncthreads();
    }
    int incl = sc[t];
    rp[i] = incl - v;
    if (t == 255) part[b] = incl;
}

__global__ void scan2_kernel(int* __restrict__ p) {
    __shared__ int sc[256];
    __shared__ int carry_s;
    int t = threadIdx.x;
    if (t == 0) carry_s = 0;
    __syncthreads();
    for (int base = 0; base < NPART; base += 256) {
        int i = base + t;
        int v = (i < NPART) ? p[i] : 0;
        sc[t] = v; __syncthreads();
        for (int off = 1; off < 256; off <<= 1) {
            int x = (t >= off) ? sc[t - off] : 0;
            __syncthreads();
            sc[t] += x;
            __syncthreads();
        }
        int incl = sc[t];
        int carry = carry_s;
        if (i < NPART) p[i] = carry + incl - v;
        __syncthreads();
        if (t == 255) carry_s = carry + incl;
        __syncthreads();
    }
    if (t == 0) p[NPART] = carry_s;   // == NEDGE
}

__global__ void scan3_kernel(int* __restrict__ rp, int* __restrict__ cursor,
                             const int* __restrict__ part) {
    int i = blockIdx.x * 256 + threadIdx.x;
    if (i < NKEY) {
        int v = rp[i] + part[i >> 8];
        rp[i] = v;
        cursor[i] = v;
    } else if (i == NKEY) {
        rp[i] = part[NPART];
    }
}

// perm[pos] = (row_in_block << 16) | src   (src < 50000 fits 16 bits)
__global__ void scatter_kernel(const int* __restrict__ ei, const int* __restrict__ et,
                               int* __restrict__ cursor, int* __restrict__ perm) {
    int e = blockIdx.x * 256 + threadIdx.x;
    if (e < NEDGE) {
        int d = ei[NEDGE + e];
        int pos = atomicAdd(&cursor[edge_key(d, et[e])], 1);
        perm[pos] = ((d & 63) << 16) | ei[e];
    }
}

// ---------- W^T prep: fragment-ordered layout ----------
// WT[r] is 91 fragments (ks 0..6, nt 0..12), each a contiguous 1024 B block
// consumed by one wave as lane*16. Group g = r*7+ks has its 13 nt-fragments
// at byte offset (13*g + nt)*1024 -> the whole WT is a linear 119 x 13 KB
// stream for the fused kernel's staging pipeline. r==16 is root.
__global__ void wt_kernel(const float* __restrict__ W, const float* __restrict__ root,
                          unsigned short* __restrict__ WT) {
    int idx = blockIdx.x * 256 + threadIdx.x;
    if (idx >= WTSZ) return;
    int r = idx / WTREL;
    int rem = idx - r * WTREL;
    int blk = rem >> 9;            // 0..90 = ks*13 + nt
    int within = rem & 511;
    int ks = blk / 13;
    int nt = blk - ks * 13;
    int lane = within >> 3;
    int j = within & 7;
    int mn = lane & 15, quad = lane >> 4;
    int n = nt * 16 + mn;
    int k = ks * 32 + quad * 8 + j;
    float v = 0.f;
    if (n < DIM && k < DIM)
        v = (r < 16) ? W[((size_t)r * DIM + k) * DIM + n] : root[(size_t)k * DIM + n];
    WT[idx] = f2bf(v);
}

// ---------- fused layer ----------
// Lockstep barrier-clocked pipeline over 119 (relation, ks) B-groups, staged
// into an LDS double buffer with DIRECT global->LDS DMA:
//   iter g: stage(g+1) via 3-4 global_load_lds_dwordx4 (one per 1024 B
//           fragment: wave-uniform LDS base, per-lane global src lane*16);
//           [gather(rel) if ks==0 — B loads fly under it];
//           process(g) (1 af + 13 bf ds_read_b128 + 13 MFMA);
//           __syncthreads() (its vmcnt(0) drain IS the stage sync).
// vs R5's reg-staging: no ds_writes, no register round-trip, no conservative
// vmem wait before LDS writes (nothing consumes the staged loads in-register),
// no RA/RB arrays (-32 VGPR, removes the spill that caused WRITE_SIZE 68 MB).
// LDS = 25.7 (As) + 26 (B dbuf) + 5 (pLds) = 57.4 KB -> 2 blocks/CU.
template<bool SRC_F32, bool OUT_RELU_BF16>
__global__ __launch_bounds__(256, 2) void fused_kernel(
        const void* __restrict__ srcv, const unsigned short* __restrict__ WT,
        const int* __restrict__ rp, const int* __restrict__ perm,
        const float* __restrict__ bias, void* __restrict__ outv) {
    __shared__ __align__(16) char As[25664];   // 64 rows x 400 B bf16 + 64 B slack
    __shared__ __align__(16) char Bs[2 * BFRAG];
    __shared__ int pLds[PCAP];                 // staged perm segment for this block
    const int t = threadIdx.x;
    const int w = t >> 6;
    const int lane = t & 63;
    const int quad = lane >> 4;
    const int mn = lane & 15;
    const int v0 = blockIdx.x * 64;
    const int kbase = blockIdx.x * 1024;
    const bool colok = (lane < 50);

    // descriptor loads overlap the LDS zeroing
    const int li = (lane < 16) ? lane : 15;
    const int b0 = rp[kbase + li * 64 + (w << 4)];
    const int b1 = rp[kbase + li * 64 + (w << 4) + 16];
    const int pbase = rp[kbase];             // block's perm segment [pbase, pend)
    const int pend  = rp[kbase + 1024];
    const int pcnt  = pend - pbase;
    const bool staged = (pcnt <= PCAP);      // block-uniform

    for (int i = t; i < 25664 / 16; i += 256)
        *(float4*)(As + i * 16) = make_float4(0.f, 0.f, 0.f, 0.f);
    if (staged)
        for (int i = t; i < pcnt; i += 256) pLds[i] = perm[pbase + i];

    const float* srcf = (const float*)srcv;
    const unsigned short* srcb = (const unsigned short*)srcv;

    floatx4 acc[13];
    #pragma unroll
    for (int i = 0; i < 13; ++i) acc[i] = (floatx4){0.f, 0.f, 0.f, 0.f};

    // ---- stage: one global_load_lds_dwordx4 per 1024 B fragment ----
    // LDS dest = uniform base (HW adds lane*16); global src = per-lane.
    auto stage_frag = [&](int g, int frag) {
        const char* src = (const char*)WT + ((size_t)(13 * g + frag) << 10) + (lane << 4);
        char* dst = Bs + (g & 1) * BFRAG + (frag << 10);
        __builtin_amdgcn_global_load_lds((gas_u32*)(const void*)src,
                                         (las_u32*)(void*)dst, 16, 0, 0);
    };
    auto stage = [&](int g) {
        #pragma unroll
        for (int i = 0; i < 3; ++i) stage_frag(g, (i << 2) + w);
        if (w == 0) stage_frag(g, 12);
    };
    auto process = [&](int g, int ks) {          // 1 af ds_read + 13 bf ds_read + 13 MFMA
        const short8 af = *(const short8*)(As + ((w << 4) + mn) * 400 + (quad << 4) + ks * 64);
        const char* bb = Bs + (g & 1) * BFRAG + (lane << 4);
        short8 bf[13];
        #pragma unroll
        for (int nt = 0; nt < 13; ++nt)
            bf[nt] = *(const short8*)(bb + nt * 1024);
        #pragma unroll
        for (int nt = 0; nt < 13; ++nt)
            acc[nt] = __builtin_amdgcn_mfma_f32_16x16x32_bf16(af, bf[nt], acc[nt], 0, 0, 0);
    };
    auto zero_rows = [&]() {   // zero this wave's 16 rows (6400 B)
        char* base = As + w * 6400;
        #pragma unroll
        for (int i = 0; i < 6; ++i)
            *(float4*)(base + i * 1024 + lane * 16) = make_float4(0.f, 0.f, 0.f, 0.f);
        if (lane < 16)
            *(float4*)(base + 6144 + lane * 16) = make_float4(0.f, 0.f, 0.f, 0.f);
    };

    auto gather = [&](int rel) {   // fill As (wave-private rows) for relation rel
        zero_rows();
        if (rel < NREL) {
            const int ws = __builtin_amdgcn_readlane(b0, rel);
            const int we = __builtin_amdgcn_readlane(b1, rel);
            if (ws >= we) return;
            int curM = -1, curCnt = 0;
            float s0 = 0.f, s1 = 0.f, s2 = 0.f, s3 = 0.f;
            auto flush = [&]() {
                if (curM >= 0 && colok) {
                    float sc = 1.0f / (float)curCnt;
                    ushort4 pk;
                    pk.x = f2bf(s0 * sc); pk.y = f2bf(s1 * sc);
                    pk.z = f2bf(s2 * sc); pk.w = f2bf(s3 * sc);
                    *(ushort4*)(As + curM * 400 + lane * 8) = pk;
                }
            };
            for (int jb = ws; jb < we; jb += MAXB) {
                const int nb = min(we - jb, MAXB);
                const int sel = (lane < nb) ? lane : (nb - 1);
                int pmv;
                if (staged) pmv = pLds[jb - pbase + sel];
                else        pmv = perm[jb + sel];
                int pms[MAXB];
                #pragma unroll
                for (int i = 0; i < MAXB; ++i)
                    pms[i] = __builtin_amdgcn_readlane(pmv, i);
                float4  qf[MAXB];
                ushort4 qb[MAXB];
                #pragma unroll
                for (int i = 0; i < MAXB; ++i) {
                    if (i < nb && colok) {
                        const int sv = pms[i] & 0xFFFF;
                        if (SRC_F32) qf[i] = *(const float4*)(srcf + (size_t)sv * DIM + (lane << 2));
                        else         qb[i] = *(const ushort4*)(srcb + (size_t)sv * DIM + (lane << 2));
                    }
                }
                #pragma unroll
                for (int i = 0; i < MAXB; ++i) {
                    if (i < nb) {
                        const int m = pms[i] >> 16;
                        float f0, f1, f2, f3;
                        if (SRC_F32) { f0 = qf[i].x; f1 = qf[i].y; f2 = qf[i].z; f3 = qf[i].w; }
                        else { f0 = bf2f(qb[i].x); f1 = bf2f(qb[i].y); f2 = bf2f(qb[i].z); f3 = bf2f(qb[i].w); }
                        if (m != curM) {
                            flush();
                            curM = m; curCnt = 1;
                            s0 = f0; s1 = f1; s2 = f2; s3 = f3;
                        } else {
                            ++curCnt;
                            s0 += f0; s1 += f1; s2 += f2; s3 += f3;
                        }
                    }
                }
            }
            flush();
        } else {
            // root: A = x rows directly (two batches of 8 independent loads)
            #pragma unroll
            for (int g2 = 0; g2 < 2; ++g2) {
                float4  qf[8];
                ushort4 qb[8];
                #pragma unroll
                for (int i = 0; i < 8; ++i) {
                    const int v = v0 + (w << 4) + g2 * 8 + i;
                    if (v < NNODES && colok) {
                        if (SRC_F32) qf[i] = *(const float4*)(srcf + (size_t)v * DIM + (lane << 2));
                        else         qb[i] = *(const ushort4*)(srcb + (size_t)v * DIM + (lane << 2));
                    }
                }
                #pragma unroll
                for (int i = 0; i < 8; ++i) {
                    const int m = (w << 4) + g2 * 8 + i;
                    if (v0 + m < NNODES && colok) {
                        ushort4 pk;
                        if (SRC_F32) {
                            pk.x = f2bf(qf[i].x); pk.y = f2bf(qf[i].y);
                            pk.z = f2bf(qf[i].z); pk.w = f2bf(qf[i].w);
                        } else pk = qb[i];
                        *(ushort4*)(As + m * 400 + lane * 8) = pk;
                    }
                }
            }
        }
    };

    // ---- prologue: stage group 0; one barrier covers As-zero + pLds + stage ----
    stage(0);
    __syncthreads();

    // ---- main loop: one barrier per group; barrier's vmcnt(0) syncs the DMA ----
    int ks = 0, rel = 0;
    #pragma unroll 1
    for (int g = 0; g < GTOT; ++g) {
        if (g + 1 < GTOT) stage(g + 1);     // DMA flies under gather/process
        if (ks == 0) gather(rel);
        process(g, ks);
        __syncthreads();
        if (++ks == 7) { ks = 0; ++rel; }
    }

    // epilogue: C row = quad*4 + i, col = nt*16 + mn
    float* outf = (float*)outv;
    unsigned short* outb = (unsigned short*)outv;
    #pragma unroll
    for (int nt = 0; nt < 13; ++nt) {
        const int col = nt * 16 + mn;
        if (col < DIM) {
            const float bv = bias[col];
            #pragma unroll
            for (int i = 0; i < 4; ++i) {
                const int v = v0 + (w << 4) + (quad << 2) + i;
                if (v < NNODES) {
                    float x = acc[nt][i] + bv;
                    if (OUT_RELU_BF16) {
                        x = fmaxf(x, 0.f);
                        outb[(size_t)v * DIM + col] = f2bf(x);
                    } else {
                        outf[(size_t)v * DIM + col] = x;
                    }
                }
            }
        }
    }
}

// ---------- launch ----------

extern "C" void kernel_launch(void* const* d_in, const int* in_sizes, int n_in,
                              void* d_out, int out_size, void* d_ws, size_t ws_size,
                              hipStream_t stream) {
    const int*   edge_index = (const int*)d_in[0];
    const int*   edge_type  = (const int*)d_in[1];
    const float* emb   = (const float*)d_in[2];
    const float* W1    = (const float*)d_in[3];
    const float* root1 = (const float*)d_in[4];
    const float* b1    = (const float*)d_in[5];
    const float* W2    = (const float*)d_in[6];
    const float* root2 = (const float*)d_in[7];
    const float* b2    = (const float*)d_in[8];
    float* out = (float*)d_out;

    // ws layout (bytes):
    //  cnt/cursor  0           3,203,072   (cnt dead after scan1; reused as cursor)
    //  rp          3,203,072   3,203,080
    //  part        6,406,152      12,520
    //  perm        6,418,672   1,600,000
    //  hbf         8,018,672  20,000,000
    //  WT1        28,018,672   1,584,128
    //  WT2        29,602,800   1,584,128   -> total ~31.2 MB
    char* ws = (char*)d_ws;
    int*            cnt    = (int*)(ws);
    int*            cursor = (int*)(ws);
    int*            rp     = (int*)(ws + 3203072);
    int*            part   = (int*)(ws + 6406152);
    int*            perm   = (int*)(ws + 6418672);
    unsigned short* hbf    = (unsigned short*)(ws + 8018672);
    unsigned short* WT1    = (unsigned short*)(ws + 28018672);
    unsigned short* WT2    = (unsigned short*)(ws + 29602800);

    hipMemsetAsync(cnt, 0, (size_t)NKEY * sizeof(int), stream);
    count_kernel<<<(NEDGE + 255) / 256, 256, 0, stream>>>(edge_index, edge_type, cnt);
    scan1_kernel<<<NPART, 256, 0, stream>>>(cnt, rp, part);
    scan2_kernel<<<1, 256, 0, stream>>>(part);
    scan3_kernel<<<(NKEY + 256) / 256 + 1, 256, 0, stream>>>(rp, cursor, part);
    scatter_kernel<<<(NEDGE + 255) / 256, 256, 0, stream>>>(edge_index, edge_type, cursor, perm);

    wt_kernel<<<(WTSZ + 255) / 256, 256, 0, stream>>>(W1, root1, WT1);
    wt_kernel<<<(WTSZ + 255) / 256, 256, 0, stream>>>(W2, root2, WT2);

    fused_kernel<true, true><<<NBLK, 256, 0, stream>>>(emb, WT1, rp, perm, b1, hbf);
    fused_kernel<false, false><<<NBLK, 256, 0, stream>>>(hbf, WT2, rp, perm, b2, out);
}

// Round 8
// 560.383 us; speedup vs baseline: 1.6906x; 1.1311x over previous
//
#include <hip/hip_runtime.h>
#include <cstdint>
#include <cstddef>

#define NNODES 50000
#define NREL   16
#define DIM    200
#define NEDGE  400000
#define BROWS  224                      // rows per block = 7 waves x 32
#define NBLK   224                      // ceil(50000/224) -> 1 block per CU, single round
#define KPB    3584                     // keys per block = NREL * BROWS
#define NKEY   (NBLK * KPB)             // 802816, key = (d/224)*3584 + r*224 + (d%224)
#define NPART  (NKEY / 256)             // 3136
#define WTREL  46592                    // elements per relation tile: 91 frags x 512
#define WTSZ   (17 * WTREL)             // 17 relation tiles (16 + root)
#define MAXB   16                       // batched gathers (wave-chunk deg: Poisson λ=16)
#define PCAP   2304                     // per-block perm staging cap (expected 1786)
#define GTOT   119                      // 17 relations x 7 ks-groups, linear stream
#define BFRAG  13312                    // 13 fragments x 1024 B staged per group
#define ASZ    (BROWS * 400 + 64)       // 89664 B

typedef __attribute__((ext_vector_type(8))) short short8;   // 8 bf16
typedef __attribute__((ext_vector_type(4))) float floatx4;  // MFMA C/D

typedef __attribute__((address_space(1))) const unsigned int gas_u32;
typedef __attribute__((address_space(3))) unsigned int las_u32;

__device__ __forceinline__ unsigned short f2bf(float f) {
    unsigned int u = __float_as_uint(f);
    u = (u + 0x7FFFu + ((u >> 16) & 1u)) >> 16;   // RNE
    return (unsigned short)u;
}
__device__ __forceinline__ float bf2f(unsigned short h) {
    return __uint_as_float(((unsigned int)h) << 16);
}

// ---------- preprocessing: counting sort by block-major key ----------

__device__ __forceinline__ int edge_key(int d, int r) {
    return (d / BROWS) * KPB + r * BROWS + (d % BROWS);
}

__global__ void count_kernel(const int* __restrict__ ei, const int* __restrict__ et,
                             int* __restrict__ cnt) {
    int e = blockIdx.x * 256 + threadIdx.x;
    if (e < NEDGE) atomicAdd(&cnt[edge_key(ei[NEDGE + e], et[e])], 1);
}

__global__ void scan1_kernel(const int* __restrict__ cnt, int* __restrict__ rp,
                             int* __restrict__ part) {
    __shared__ int sc[256];
    int b = blockIdx.x, t = threadIdx.x, i = b * 256 + t;
    int v = cnt[i];
    sc[t] = v; __syncthreads();
    for (int off = 1; off < 256; off <<= 1) {
        int x = (t >= off) ? sc[t - off] : 0;
        __syncthreads();
        sc[t] += x;
        __syncthreads();
    }
    int incl = sc[t];
    rp[i] = incl - v;
    if (t == 255) part[b] = incl;
}

__global__ void scan2_kernel(int* __restrict__ p) {
    __shared__ int sc[256];
    __shared__ int carry_s;
    int t = threadIdx.x;
    if (t == 0) carry_s = 0;
    __syncthreads();
    for (int base = 0; base < NPART; base += 256) {
        int i = base + t;
        int v = (i < NPART) ? p[i] : 0;
        sc[t] = v; __syncthreads();
        for (int off = 1; off < 256; off <<= 1) {
            int x = (t >= off) ? sc[t - off] : 0;
            __syncthreads();
            sc[t] += x;
            __syncthreads();
        }
        int incl = sc[t];
        int carry = carry_s;
        if (i < NPART) p[i] = carry + incl - v;
        __syncthreads();
        if (t == 255) carry_s = carry + incl;
        __syncthreads();
    }
    if (t == 0) p[NPART] = carry_s;   // == NEDGE
}

__global__ void scan3_kernel(int* __restrict__ rp, int* __restrict__ cursor,
                             const int* __restrict__ part) {
    int i = blockIdx.x * 256 + threadIdx.x;
    if (i < NKEY) {
        int v = rp[i] + part[i >> 8];
        rp[i] = v;
        cursor[i] = v;
    } else if (i == NKEY) {
        rp[i] = part[NPART];
    }
}

// perm[pos] = (row_in_block << 16) | src   (src < 50000 fits 16 bits, row < 224)
__global__ void scatter_kernel(const int* __restrict__ ei, const int* __restrict__ et,
                               int* __restrict__ cursor, int* __restrict__ perm) {
    int e = blockIdx.x * 256 + threadIdx.x;
    if (e < NEDGE) {
        int d = ei[NEDGE + e];
        int pos = atomicAdd(&cursor[edge_key(d, et[e])], 1);
        perm[pos] = ((d % BROWS) << 16) | ei[e];
    }
}

// ---------- W^T prep: fragment-ordered layout (unchanged geometry) ----------
// WT[r] is 91 fragments (ks 0..6, nt 0..12), each a contiguous 1024 B block
// consumed by one wave as lane*16. Group g = r*7+ks has its 13 nt-fragments
// at byte offset (13*g + nt)*1024. r==16 is root.
__global__ void wt_kernel(const float* __restrict__ W, const float* __restrict__ root,
                          unsigned short* __restrict__ WT) {
    int idx = blockIdx.x * 256 + threadIdx.x;
    if (idx >= WTSZ) return;
    int r = idx / WTREL;
    int rem = idx - r * WTREL;
    int blk = rem >> 9;            // 0..90 = ks*13 + nt
    int within = rem & 511;
    int ks = blk / 13;
    int nt = blk - ks * 13;
    int lane = within >> 3;
    int j = within & 7;
    int mn = lane & 15, quad = lane >> 4;
    int n = nt * 16 + mn;
    int k = ks * 32 + quad * 8 + j;
    float v = 0.f;
    if (n < DIM && k < DIM)
        v = (r < 16) ? W[((size_t)r * DIM + k) * DIM + n] : root[(size_t)k * DIM + n];
    WT[idx] = f2bf(v);
}

// ---------- fused layer ----------
// R6's proven DMA double-buffer template, re-tiled:
//  - wave owns 32 rows (2 M-tiles): each bf LDS read feeds 2 MFMAs (accA/accB)
//    -> B LDS-read traffic per output row HALVES.
//  - block = 7 waves x 32 = 224 rows -> grid 224 = 1 block/CU, single round:
//    per-CU barrier-tick count drops 363 -> 119.
// Per tick: stage(g+1) via 1-2 global_load_lds_dwordx4 per wave; gather at
// ks==0 (wave-private As rows); process = 2 af + 13 bf ds_read_b128 + 26 MFMA;
// __syncthreads (vmcnt(0) drain = stage sync; DMA has the whole tick to land).
// LDS = 87.6 (As) + 26 (B dbuf) + 9 (pLds) = 122.6 KB -> 1 block/CU, 7 waves.
template<bool SRC_F32, bool OUT_RELU_BF16>
__global__ __launch_bounds__(448, 2) void fused_kernel(
        const void* __restrict__ srcv, const unsigned short* __restrict__ WT,
        const int* __restrict__ rp, const int* __restrict__ perm,
        const float* __restrict__ bias, void* __restrict__ outv) {
    __shared__ __align__(16) char As[ASZ];     // 224 rows x 400 B bf16 + 64 B slack
    __shared__ __align__(16) char Bs[2 * BFRAG];
    __shared__ int pLds[PCAP];                 // staged perm segment for this block
    const int t = threadIdx.x;
    const int w = t >> 6;                      // 0..6
    const int lane = t & 63;
    const int quad = lane >> 4;
    const int mn = lane & 15;
    const int v0 = blockIdx.x * BROWS;
    const int kbase = blockIdx.x * KPB;
    const bool colok = (lane < 50);

    // descriptor loads overlap the LDS zeroing
    const int li = (lane < 16) ? lane : 15;
    const int b0 = rp[kbase + li * BROWS + (w << 5)];
    const int b1 = rp[kbase + li * BROWS + (w << 5) + 32];
    const int pbase = rp[kbase];             // block's perm segment [pbase, pend)
    const int pend  = rp[kbase + KPB];
    const int pcnt  = pend - pbase;
    const bool staged = (pcnt <= PCAP);      // block-uniform

    for (int i = t; i < ASZ / 16; i += 448)
        *(float4*)(As + i * 16) = make_float4(0.f, 0.f, 0.f, 0.f);
    if (staged)
        for (int i = t; i < pcnt; i += 448) pLds[i] = perm[pbase + i];

    const float* srcf = (const float*)srcv;
    const unsigned short* srcb = (const unsigned short*)srcv;

    floatx4 accA[13], accB[13];
    #pragma unroll
    for (int i = 0; i < 13; ++i) {
        accA[i] = (floatx4){0.f, 0.f, 0.f, 0.f};
        accB[i] = (floatx4){0.f, 0.f, 0.f, 0.f};
    }

    // ---- stage: one global_load_lds_dwordx4 per 1024 B fragment ----
    auto stage_frag = [&](int g, int frag) {
        const char* src = (const char*)WT + ((size_t)(13 * g + frag) << 10) + (lane << 4);
        char* dst = Bs + (g & 1) * BFRAG + (frag << 10);
        __builtin_amdgcn_global_load_lds((gas_u32*)(const void*)src,
                                         (las_u32*)(void*)dst, 16, 0, 0);
    };
    auto stage = [&](int g) {
        stage_frag(g, w);
        if (w < 6) stage_frag(g, w + 7);
    };
    auto process = [&](int g, int ks) {   // 2 af + 13 bf ds_read_b128, 26 MFMA
        const char* abase = As + ((w << 5) + mn) * 400 + (quad << 4) + ks * 64;
        const short8 af0 = *(const short8*)(abase);
        const short8 af1 = *(const short8*)(abase + 16 * 400);
        const char* bb = Bs + (g & 1) * BFRAG + (lane << 4);
        #pragma unroll
        for (int nt = 0; nt < 13; ++nt) {
            const short8 bf = *(const short8*)(bb + nt * 1024);
            accA[nt] = __builtin_amdgcn_mfma_f32_16x16x32_bf16(af0, bf, accA[nt], 0, 0, 0);
            accB[nt] = __builtin_amdgcn_mfma_f32_16x16x32_bf16(af1, bf, accB[nt], 0, 0, 0);
        }
    };
    auto zero_rows = [&]() {   // zero this wave's 32 rows (12800 B)
        char* base = As + w * 12800;
        #pragma unroll
        for (int i = 0; i < 12; ++i)
            *(float4*)(base + i * 1024 + lane * 16) = make_float4(0.f, 0.f, 0.f, 0.f);
        if (lane < 32)
            *(float4*)(base + 12288 + lane * 16) = make_float4(0.f, 0.f, 0.f, 0.f);
    };

    auto gather = [&](int rel) {   // fill As (wave-private 32 rows) for relation rel
        zero_rows();
        if (rel < NREL) {
            const int ws = __builtin_amdgcn_readlane(b0, rel);
            const int we = __builtin_amdgcn_readlane(b1, rel);
            if (ws >= we) return;
            int curM = -1, curCnt = 0;
            float s0 = 0.f, s1 = 0.f, s2 = 0.f, s3 = 0.f;
            auto flush = [&]() {
                if (curM >= 0 && colok) {
                    float sc = 1.0f / (float)curCnt;
                    ushort4 pk;
                    pk.x = f2bf(s0 * sc); pk.y = f2bf(s1 * sc);
                    pk.z = f2bf(s2 * sc); pk.w = f2bf(s3 * sc);
                    *(ushort4*)(As + curM * 400 + lane * 8) = pk;
                }
            };
            for (int jb = ws; jb < we; jb += MAXB) {
                const int nb = min(we - jb, MAXB);
                const int sel = (lane < nb) ? lane : (nb - 1);
                int pmv;
                if (staged) pmv = pLds[jb - pbase + sel];
                else        pmv = perm[jb + sel];
                int pms[MAXB];
                #pragma unroll
                for (int i = 0; i < MAXB; ++i)
                    pms[i] = __builtin_amdgcn_readlane(pmv, i);
                float4  qf[MAXB];
                ushort4 qb[MAXB];
                #pragma unroll
                for (int i = 0; i < MAXB; ++i) {
                    if (i < nb && colok) {
                        const int sv = pms[i] & 0xFFFF;
                        if (SRC_F32) qf[i] = *(const float4*)(srcf + (size_t)sv * DIM + (lane << 2));
                        else         qb[i] = *(const ushort4*)(srcb + (size_t)sv * DIM + (lane << 2));
                    }
                }
                #pragma unroll
                for (int i = 0; i < MAXB; ++i) {
                    if (i < nb) {
                        const int m = pms[i] >> 16;
                        float f0, f1, f2, f3;
                        if (SRC_F32) { f0 = qf[i].x; f1 = qf[i].y; f2 = qf[i].z; f3 = qf[i].w; }
                        else { f0 = bf2f(qb[i].x); f1 = bf2f(qb[i].y); f2 = bf2f(qb[i].z); f3 = bf2f(qb[i].w); }
                        if (m != curM) {
                            flush();
                            curM = m; curCnt = 1;
                            s0 = f0; s1 = f1; s2 = f2; s3 = f3;
                        } else {
                            ++curCnt;
                            s0 += f0; s1 += f1; s2 += f2; s3 += f3;
                        }
                    }
                }
            }
            flush();
        } else {
            // root: A = x rows directly (four batches of 8 independent loads)
            #pragma unroll
            for (int g2 = 0; g2 < 4; ++g2) {
                float4  qf[8];
                ushort4 qb[8];
                #pragma unroll
                for (int i = 0; i < 8; ++i) {
                    const int v = v0 + (w << 5) + g2 * 8 + i;
                    if (v < NNODES && colok) {
                        if (SRC_F32) qf[i] = *(const float4*)(srcf + (size_t)v * DIM + (lane << 2));
                        else         qb[i] = *(const ushort4*)(srcb + (size_t)v * DIM + (lane << 2));
                    }
                }
                #pragma unroll
                for (int i = 0; i < 8; ++i) {
                    const int m = (w << 5) + g2 * 8 + i;
                    if (v0 + m < NNODES && colok) {
                        ushort4 pk;
                        if (SRC_F32) {
                            pk.x = f2bf(qf[i].x); pk.y = f2bf(qf[i].y);
                            pk.z = f2bf(qf[i].z); pk.w = f2bf(qf[i].w);
                        } else pk = qb[i];
                        *(ushort4*)(As + m * 400 + lane * 8) = pk;
                    }
                }
            }
        }
    };

    // ---- prologue: stage group 0; one barrier covers As-zero + pLds + stage ----
    stage(0);
    __syncthreads();

    // ---- main loop: one barrier per group; barrier's vmcnt(0) syncs the DMA ----
    int ks = 0, rel = 0;
    #pragma unroll 1
    for (int g = 0; g < GTOT; ++g) {
        if (g + 1 < GTOT) stage(g + 1);     // DMA flies under gather/process
        if (ks == 0) gather(rel);
        process(g, ks);
        __syncthreads();
        if (++ks == 7) { ks = 0; ++rel; }
    }

    // epilogue: two 16-row tiles; C row = quad*4 + i, col = nt*16 + mn
    float* outf = (float*)outv;
    unsigned short* outb = (unsigned short*)outv;
    #pragma unroll
    for (int nt = 0; nt < 13; ++nt) {
        const int col = nt * 16 + mn;
        if (col < DIM) {
            const float bv = bias[col];
            #pragma unroll
            for (int i = 0; i < 4; ++i) {
                const int m  = (w << 5) + (quad << 2) + i;
                const int vA = v0 + m;
                const int vB = vA + 16;
                if (vA < NNODES) {
                    float x = accA[nt][i] + bv;
                    if (OUT_RELU_BF16) {
                        x = fmaxf(x, 0.f);
                        outb[(size_t)vA * DIM + col] = f2bf(x);
                    } else {
                        outf[(size_t)vA * DIM + col] = x;
                    }
                }
                if (vB < NNODES) {
                    float x = accB[nt][i] + bv;
                    if (OUT_RELU_BF16) {
                        x = fmaxf(x, 0.f);
                        outb[(size_t)vB * DIM + col] = f2bf(x);
                    } else {
                        outf[(size_t)vB * DIM + col] = x;
                    }
                }
            }
        }
    }
}

// ---------- launch ----------

extern "C" void kernel_launch(void* const* d_in, const int* in_sizes, int n_in,
                              void* d_out, int out_size, void* d_ws, size_t ws_size,
                              hipStream_t stream) {
    const int*   edge_index = (const int*)d_in[0];
    const int*   edge_type  = (const int*)d_in[1];
    const float* emb   = (const float*)d_in[2];
    const float* W1    = (const float*)d_in[3];
    const float* root1 = (const float*)d_in[4];
    const float* b1    = (const float*)d_in[5];
    const float* W2    = (const float*)d_in[6];
    const float* root2 = (const float*)d_in[7];
    const float* b2    = (const float*)d_in[8];
    float* out = (float*)d_out;

    // ws layout (bytes) — COMPACTED with lifetime aliasing; total 27,979,536 B,
    // 3.2 MB UNDER the R0-R6 proven footprint (R7's 31.2 MB layout is the prime
    // container-failure suspect: +16.4 KB past every previously-validated bound).
    //  WT1         0          1,584,128   (1024-aligned DMA source)
    //  WT2         1,584,128  1,584,128   (1024-aligned)
    //  rp          3,168,256  3,211,268   (NKEY+1 ints; live through both fused)
    //  perm        6,379,536  1,600,000   (16-aligned)
    //  hbf         7,979,536 20,000,000   (written AFTER scatter completes)
    //    cnt/cursor  aliases hbf+0        3,211,264  (dead after scatter)
    //    part        aliases hbf+3,211,264   12,548  (dead after scan3)
    char* ws = (char*)d_ws;
    unsigned short* WT1    = (unsigned short*)(ws);
    unsigned short* WT2    = (unsigned short*)(ws + 1584128);
    int*            rp     = (int*)(ws + 3168256);
    int*            perm   = (int*)(ws + 6379536);
    unsigned short* hbf    = (unsigned short*)(ws + 7979536);
    int*            cnt    = (int*)(ws + 7979536);             // alias (pre-hbf lifetime)
    int*            cursor = (int*)(ws + 7979536);             // alias (pre-hbf lifetime)
    int*            part   = (int*)(ws + 7979536 + 3211264);   // alias (pre-hbf lifetime)

    hipMemsetAsync(cnt, 0, (size_t)NKEY * sizeof(int), stream);
    count_kernel<<<(NEDGE + 255) / 256, 256, 0, stream>>>(edge_index, edge_type, cnt);
    scan1_kernel<<<NPART, 256, 0, stream>>>(cnt, rp, part);
    scan2_kernel<<<1, 256, 0, stream>>>(part);
    scan3_kernel<<<(NKEY + 256) / 256 + 1, 256, 0, stream>>>(rp, cursor, part);
    scatter_kernel<<<(NEDGE + 255) / 256, 256, 0, stream>>>(edge_index, edge_type, cursor, perm);

    wt_kernel<<<(WTSZ + 255) / 256, 256, 0, stream>>>(W1, root1, WT1);
    wt_kernel<<<(WTSZ + 255) / 256, 256, 0, stream>>>(W2, root2, WT2);

    fused_kernel<true, true><<<NBLK, 448, 0, stream>>>(emb, WT1, rp, perm, b1, hbf);
    fused_kernel<false, false><<<NBLK, 448, 0, stream>>>(hbf, WT2, rp, perm, b2, out);
}